// Round 10
// baseline (55887.427 us; speedup 1.0000x reference)
//
#include <hip/hip_runtime.h>

#define RS 1024   // reservoir
#define SL 4096   // seq len
#define NB 1024   // batch
#define NI 16     // input size
#define NGP 16    // group pairs; stream A = group p, stream B = group p+16
#define WPG 8     // WGs per group

typedef short s8v __attribute__((ext_vector_type(8)));
typedef float f16v __attribute__((ext_vector_type(16)));
typedef unsigned int u4v __attribute__((ext_vector_type(4)));

#define WAIT_VM0 do { asm volatile("s_waitcnt vmcnt(0)" ::: "memory"); \
                      __builtin_amdgcn_sched_barrier(0); } while (0)

static __device__ __forceinline__ unsigned short f2bf(float f) {
  unsigned u = __float_as_uint(f);
  u += 0x7fffu + ((u >> 16) & 1u);          // round-to-nearest-even
  return (unsigned short)(u >> 16);
}
static __device__ __forceinline__ float bf2f(unsigned short b) {
  return __uint_as_float(((unsigned)b) << 16);
}
static __device__ __forceinline__ float fast_tanh(float a) {
  float e = __expf(2.0f * a);               // saturates correctly at +/-inf
  return 1.0f - 2.0f / (e + 1.0f);
}

// ---- L1+L2-bypassing ops (sc0 sc1): read/write at the coherent LLC ----
static __device__ __forceinline__ u4v ld_llc_b128(const void* p) {
  u4v d;
  asm volatile("global_load_dwordx4 %0, %1, off sc0 sc1"
               : "=v"(d) : "v"(p) : "memory");
  return d;
}
static __device__ __forceinline__ void st_llc_b128(void* p, u4v d) {
  asm volatile("global_store_dwordx4 %0, %1, off sc0 sc1"
               : : "v"(p), "v"(d) : "memory");
}
static __device__ __forceinline__ void st_llc_b32(void* p, int d) {
  asm volatile("global_store_dword %0, %1, off sc0 sc1"
               : : "v"(p), "v"(d) : "memory");
}
static __device__ __forceinline__ int ld_llc_b32(const void* p) {
  int d;
  asm volatile("global_load_dword %0, %1, off sc0 sc1\n\ts_waitcnt vmcnt(0)"
               : "=v"(d) : "v"(p) : "memory");
  return d;
}

// prep: W fp32 -> bf16; zero h0 (buffer A); zero flags (2 arrays, 64B-spaced)
__global__ __launch_bounds__(256) void prep_kernel(
    const float* __restrict__ W, unsigned short* __restrict__ wbf,
    uint4* __restrict__ hA4, int* __restrict__ flags) {
  int idx = blockIdx.x * 256 + threadIdx.x;
  if (idx < RS * RS) wbf[idx] = f2bf(W[idx]);
  if (idx < (NB * RS) / 8) hA4[idx] = make_uint4(0u, 0u, 0u, 0u);
  if (idx < 4096) flags[idx] = 0;
}

// Dual-stream K-split recurrence: 128 WGs x 256 threads (4 waves).
// WG (p=bid&15, j=bid>>4) serves group A=p (rows 32p..) and B=p+16
// (rows 512+32p..) with ONE shared register-resident W-slice.
// Wave w: K-quarter [256w,+256) for all 128 WG cols; owns col-tile w.
// h layout (hx): h[c8][row][8] bf16. Fence-free LLC exchange (sc0sc1),
// per-producer plain-store flags, per-wave 2-producer targeted poll.
__global__ __launch_bounds__(256, 1) void esn_kernel(
    const float* __restrict__ x, const float* __restrict__ Win,
    const unsigned short* __restrict__ wbf,
    unsigned short* __restrict__ h0, unsigned short* __restrict__ h1,
    int* __restrict__ flags) {
  extern __shared__ char smem[];
  char* psm = smem;              // 64 KB: 16 partial slots [tile c][producer w]
  char* ctile = smem + 65536;    // 8 KB: 4 x (32x32 bf16) per-wave C tiles

  const int bid = blockIdx.x;
  const int p = bid & 15;        // group pair
  const int j = bid >> 4;        // WG-in-group 0..7
  const int tid = threadIdx.x;
  const int w = tid >> 6;        // wave 0..3 = K-quarter, owns col-tile w
  const int lane = tid & 63;
  const int l31 = lane & 31;
  const int hi = lane >> 5;      // k-half 0..1

  const int n0 = j * 128 + w * 32;   // wave's OWN 32-col base
  const int m0A = p * 32;            // stream A row base
  const int m0B = m0A + 512;         // stream B row base

  // ---- persistent W fragments: 4 tiles x 16 kk = 256 regs (shared A/B) ----
  s8v bw[4][16];
#pragma unroll
  for (int idx = 0; idx < 4; idx++) {
    const int c = (w + idx) & 3;
    const unsigned short* wp =
        wbf + (size_t)(j * 128 + c * 32 + l31) * RS + w * 256 + hi * 8;
#pragma unroll
    for (int kk = 0; kk < 16; kk++) bw[idx][kk] = *(const s8v*)(wp + kk * 16);
  }

  // ---- input-proj Win fragments hi/lo for OWN tile cols (shared A/B) ----
  union U8 { s8v v; unsigned short u[8]; };
  U8 whi, wlo;
  {
    const float* q = Win + (n0 + l31) * NI + hi * 8;
#pragma unroll
    for (int i = 0; i < 8; i++) {
      float f = q[i];
      unsigned short h16 = f2bf(f);
      whi.u[i] = h16;
      wlo.u[i] = f2bf(f - bf2f(h16));
    }
  }

  // flags: A array then B array (64B-spaced ints)
  int* flagsA = flags;
  int* flagsB = flags + 2048;
  int* myfA = flagsA + ((p * WPG + j) << 4);
  int* myfB = flagsB + ((p * WPG + j) << 4);
  const int* pfA0 = flagsA + ((p * WPG + 2 * w) << 4);
  const int* pfA1 = flagsA + ((p * WPG + 2 * w + 1) << 4);
  const int* pfB0 = flagsB + ((p * WPG + 2 * w) << 4);
  const int* pfB1 = flagsB + ((p * WPG + 2 * w + 1) << 4);

  const float* xrowA = x + (size_t)(m0A + l31) * SL * NI + hi * 8;
  const float* xrowB = x + (size_t)(m0B + l31) * SL * NI + hi * 8;
  const size_t abA = (((size_t)(32 * w + hi) * NB) + m0A + l31) << 4;
  const size_t abB = abA + ((size_t)512 << 4);
  char* wct = ctile + w * 2048;
  int dead = 0;

#define POLL(F0, F1, TGT)                                                   \
  if (lane == 0 && !dead) {                                                 \
    int spins = 0;                                                          \
    while (ld_llc_b32(F0) < (TGT) || ld_llc_b32(F1) < (TGT)) {              \
      __builtin_amdgcn_s_sleep(2);                                          \
      if (++spins > (1 << 14)) { dead = 1; break; }                         \
    }                                                                       \
  }

#define ISSUE_AL(AL, SRC, AB)                                               \
  _Pragma("unroll")                                                         \
  for (int kk = 0; kk < 16; kk++)                                           \
    AL[kk] = ld_llc_b128((SRC) + (AB) + (size_t)kk * (2 * NB * 16));

#define XFRAG(XA0, XA1, XH, XL)                                             \
  {                                                                         \
    float xf[8] = {XA0.x, XA0.y, XA0.z, XA0.w, XA1.x, XA1.y, XA1.z, XA1.w}; \
    _Pragma("unroll")                                                       \
    for (int i = 0; i < 8; i++) {                                           \
      unsigned short h16 = f2bf(xf[i]);                                     \
      XH.u[i] = h16;                                                        \
      XL.u[i] = f2bf(xf[i] - bf2f(h16));                                    \
    }                                                                       \
  }

#define MFMA_STREAM(AL, XH, XL, ACC)                                        \
  {                                                                         \
    f16v z = {};                                                            \
    z = __builtin_amdgcn_mfma_f32_32x32x16_bf16(XH.v, whi.v, z, 0, 0, 0);   \
    z = __builtin_amdgcn_mfma_f32_32x32x16_bf16(XL.v, whi.v, z, 0, 0, 0);   \
    ACC[0] = __builtin_amdgcn_mfma_f32_32x32x16_bf16(XH.v, wlo.v, z, 0, 0, 0); \
    f16v zz = {};                                                           \
    ACC[1] = zz; ACC[2] = zz; ACC[3] = zz;                                  \
  }                                                                         \
  _Pragma("unroll")                                                         \
  for (int kk = 0; kk < 16; kk++) {                                         \
    union AU { u4v u; s8v s; } au; au.u = AL[kk];                           \
    _Pragma("unroll")                                                       \
    for (int idx = 0; idx < 4; idx++)                                       \
      ACC[idx] = __builtin_amdgcn_mfma_f32_32x32x16_bf16(au.s, bw[idx][kk], ACC[idx], 0, 0, 0); \
  }

#define PARTIAL_WRITE(ACC)                                                  \
  _Pragma("unroll")                                                         \
  for (int idx = 1; idx < 4; idx++) {                                       \
    const int c = (w + idx) & 3;                                            \
    char* slot = psm + (((c << 2) | w) << 12) + (size_t)l31 * 4;            \
    _Pragma("unroll")                                                       \
    for (int r = 0; r < 16; r++)                                            \
      *(float*)(slot + (hi * 16 + r) * 128) = ACC[idx][r];                  \
  }

#define REDUCE_EPI(ACC, M0, HD)                                             \
  {                                                                         \
    f16v own = ACC[0];                                                      \
    _Pragma("unroll")                                                       \
    for (int idx = 1; idx < 4; idx++) {                                     \
      const int wp2 = (w + idx) & 3;                                        \
      const char* slot = psm + (((w << 2) | wp2) << 12) + (size_t)l31 * 4;  \
      _Pragma("unroll")                                                     \
      for (int r = 0; r < 16; r++)                                          \
        own[r] += *(const float*)(slot + (hi * 16 + r) * 128);              \
    }                                                                       \
    _Pragma("unroll")                                                       \
    for (int r = 0; r < 16; r++) {                                          \
      const int row = (r & 3) + 8 * (r >> 2) + 4 * hi;                      \
      *(unsigned short*)(wct + row * 64 + l31 * 2) = f2bf(fast_tanh(own[r])); \
    }                                                                       \
    asm volatile("s_waitcnt lgkmcnt(0)" ::: "memory");                      \
    __builtin_amdgcn_sched_barrier(0);                                      \
    const int row = lane >> 1, c = lane & 1;                                \
    u4v v0 = *(const u4v*)(wct + row * 64 + c * 16);                        \
    u4v v1 = *(const u4v*)(wct + row * 64 + c * 16 + 32);                   \
    char* g0 = (HD) + ((((size_t)(n0 >> 3) + c) * NB + (M0) + row) << 4);   \
    char* g1 = (HD) + ((((size_t)(n0 >> 3) + c + 2) * NB + (M0) + row) << 4); \
    st_llc_b128(g0, v0);                                                    \
    st_llc_b128(g1, v1);                                                    \
  }

  // ---- prologue: issue it=0 loads (h0 is zeroed by prep) ----
  u4v alA[16], alB[16];
  float4 xa0, xa1, xb0, xb1;
  ISSUE_AL(alB, (const char*)h0, abB)
  ISSUE_AL(alA, (const char*)h0, abA)
  xa0 = *(const float4*)(xrowA);
  xa1 = *(const float4*)(xrowA + 4);
  xb0 = *(const float4*)(xrowB);
  xb1 = *(const float4*)(xrowB + 4);

  for (int it = 0; it < SL; it++) {
    const char* hsrc = (const char*)((it & 1) ? h1 : h0);
    char* hdst = (char*)((it & 1) ? h0 : h1);
    (void)hsrc;

    // ---- P2: all 36 in-flight loads land; stream A compute ----
    WAIT_VM0;
    U8 xh, xl;
    XFRAG(xa0, xa1, xh, xl)
    f16v acc[4];
    MFMA_STREAM(alA, xh, xl, acc)

    // ---- P3: A partial-exchange + epilogue + store issue ----
    PARTIAL_WRITE(acc)
    __syncthreads();                       // bar1: partials visible
    REDUCE_EPI(acc, m0A, hdst)             // issues A-stores (fly through B)

    // ---- P4: stream B compute (alB already in regs; no waits) ----
    XFRAG(xb0, xb1, xh, xl)
    MFMA_STREAM(alB, xh, xl, acc)
    __syncthreads();                       // bar2: A partial-reads done

    // ---- P5: B partials; A-stores drained; publish flag A ----
    PARTIAL_WRITE(acc)
    WAIT_VM0;                              // A-stores (flew during MFMA B)
    __syncthreads();                       // bar3
    if (tid == 0) st_llc_b32(myfA, it + 1);
    REDUCE_EPI(acc, m0B, hdst)             // issues B-stores

    // ---- P6: poll A for next step (B-stores fly under the poll) ----
    POLL(pfA0, pfA1, it + 1)

    // ---- P7: B-stores drained; publish flag B ----
    WAIT_VM0;
    __syncthreads();                       // bar4
    if (tid == 0) st_llc_b32(myfB, it + 1);

    // ---- P8: poll B, then issue ALL next-step loads (fly across loop) ----
    POLL(pfB0, pfB1, it + 1)
    ISSUE_AL(alB, hdst, abB)
    ISSUE_AL(alA, hdst, abA)
    {
      const size_t xo = (size_t)((it + 1 < SL) ? it + 1 : 0) * NI;
      xa0 = *(const float4*)(xrowA + xo);
      xa1 = *(const float4*)(xrowA + xo + 4);
      xb0 = *(const float4*)(xrowB + xo);
      xb1 = *(const float4*)(xrowB + xo + 4);
    }
  }
#undef POLL
#undef ISSUE_AL
#undef XFRAG
#undef MFMA_STREAM
#undef PARTIAL_WRITE
#undef REDUCE_EPI
}

// y = h_final @ Wout^T + b ; h in hx layout: elem (b,k) at hx[k>>3][b][k&7]
__global__ __launch_bounds__(256) void yout_kernel(
    const unsigned short* __restrict__ h, const float* __restrict__ Wout,
    const float* __restrict__ bias, float* __restrict__ y) {
  const int tid = threadIdx.x;
  const int b = (blockIdx.x << 4) + (tid >> 4);
  const int o = tid & 15;
  const float* wr = Wout + (o << 10);
  float s = 0.0f;
  for (int k8 = 0; k8 < RS / 8; k8++) {
    const unsigned short* hc = h + (((size_t)k8 * NB + b) << 3);
#pragma unroll
    for (int i = 0; i < 8; i++) s += bf2f(hc[i]) * wr[k8 * 8 + i];
  }
  y[(b << 4) + o] = s + bias[o];
}

extern "C" void kernel_launch(void* const* d_in, const int* in_sizes, int n_in,
                              void* d_out, int out_size, void* d_ws, size_t ws_size,
                              hipStream_t stream) {
  const float* x = (const float*)d_in[0];
  const float* Win = (const float*)d_in[1];
  const float* W = (const float*)d_in[2];
  const float* Wout = (const float*)d_in[3];
  const float* bias = (const float*)d_in[4];
  float* y = (float*)d_out;

  char* ws = (char*)d_ws;
  unsigned short* h0 = (unsigned short*)ws;                  // 2 MB (final h)
  unsigned short* h1 = (unsigned short*)(ws + (1 << 21));    // 2 MB
  unsigned short* wbf = (unsigned short*)(ws + (2 << 21));   // 2 MB (W bf16)
  int* flags = (int*)(ws + 3 * (size_t)(1 << 21));           // 16 KB (A+B)

  (void)hipFuncSetAttribute((const void*)esn_kernel,
                            hipFuncAttributeMaxDynamicSharedMemorySize, 73728);

  prep_kernel<<<4096, 256, 0, stream>>>(W, wbf, (uint4*)h0, flags);
  esn_kernel<<<NGP * WPG, 256, 73728, stream>>>(x, Win, wbf, h0, h1, flags);
  yout_kernel<<<64, 256, 0, stream>>>(h0, Wout, bias, y);
}

// Round 11
// 18523.268 us; speedup vs baseline: 3.0171x; 3.0171x over previous
//
#include <hip/hip_runtime.h>

#define RS 1024   // reservoir
#define SL 4096   // seq len
#define NB 1024   // batch
#define NI 16     // input size
#define RGRP 32   // batch rows per group
#define NGRP 32   // groups
#define WPG 8     // WGs per group (8 * 128 cols = 1024)

typedef short s8v __attribute__((ext_vector_type(8)));
typedef float f16v __attribute__((ext_vector_type(16)));
typedef unsigned int u4v __attribute__((ext_vector_type(4)));

#define WAIT_VM(N) do { asm volatile("s_waitcnt vmcnt(" #N ")" ::: "memory"); \
                        __builtin_amdgcn_sched_barrier(0); } while (0)

static __device__ __forceinline__ unsigned short f2bf(float f) {
  unsigned u = __float_as_uint(f);
  u += 0x7fffu + ((u >> 16) & 1u);          // round-to-nearest-even
  return (unsigned short)(u >> 16);
}
static __device__ __forceinline__ float bf2f(unsigned short b) {
  return __uint_as_float(((unsigned)b) << 16);
}
static __device__ __forceinline__ float fast_tanh(float a) {
  float e = __expf(2.0f * a);               // saturates correctly at +/-inf
  return 1.0f - 2.0f / (e + 1.0f);
}

// ---- L1+L2-bypassing ops (sc0 sc1): read/write at the coherent LLC ----
static __device__ __forceinline__ u4v ld_llc_b128(const void* p) {
  u4v d;
  asm volatile("global_load_dwordx4 %0, %1, off sc0 sc1"
               : "=v"(d) : "v"(p) : "memory");
  return d;
}
static __device__ __forceinline__ void st_llc_b128(void* p, u4v d) {
  asm volatile("global_store_dwordx4 %0, %1, off sc0 sc1"
               : : "v"(p), "v"(d) : "memory");
}
static __device__ __forceinline__ void st_llc_b32(void* p, int d) {
  asm volatile("global_store_dword %0, %1, off sc0 sc1"
               : : "v"(p), "v"(d) : "memory");
}
// 8 flags (32B) in one shot: two dwordx4 + single drain
static __device__ __forceinline__ void ld_flags8(const void* p, u4v& a, u4v& b) {
  asm volatile("global_load_dwordx4 %0, %2, off sc0 sc1\n\t"
               "global_load_dwordx4 %1, %2, off offset:16 sc0 sc1\n\t"
               "s_waitcnt vmcnt(0)"
               : "=v"(a), "=v"(b) : "v"(p) : "memory");
}

// prep: W fp32 -> bf16; zero h0 (buffer A); zero wave-flags
__global__ __launch_bounds__(256) void prep_kernel(
    const float* __restrict__ W, unsigned short* __restrict__ wbf,
    uint4* __restrict__ hA4, int* __restrict__ flags) {
  int idx = blockIdx.x * 256 + threadIdx.x;
  if (idx < RS * RS) wbf[idx] = f2bf(W[idx]);
  if (idx < (NB * RS) / 8) hA4[idx] = make_uint4(0u, 0u, 0u, 0u);
  if (idx < 4096) flags[idx] = 0;
}

// K-split W-register-resident recurrence; fence-free LLC h-exchange with
// PER-WAVE plain-store flags + per-wave targeted 8-flag poll.
// h layout (hx): h[c8][row][8] bf16, c8 = col/8 (16B chunk per (c8,row)).
// 256 WGs x 256 threads (4 waves). Group g = bid&31 owns rows [32g,+32);
// WG j = bid>>5 owns cols [128j,+128). Wave w: K-quarter [256w,+256) for all
// 128 WG cols (B = 4x16 frags = 256 AGPR); owns+stores col-tile w.
// Wave flag (j,w') at flags[g*32+4j+w']; consumer wave w polls [8w,8w+8).
__global__ __launch_bounds__(256, 1) void esn_kernel(
    const float* __restrict__ x, const float* __restrict__ Win,
    const unsigned short* __restrict__ wbf,
    unsigned short* __restrict__ hA, unsigned short* __restrict__ hB,
    int* __restrict__ flags) {
  extern __shared__ char smem[];
  char* psm = smem;              // 64 KB: 16 partial slots [tile c][producer w]
  char* ctile = smem + 65536;    // 8 KB: 4 x (32x32 bf16) per-wave C tiles

  const int bid = blockIdx.x;
  const int g = bid & 31;        // group (same bid%8 across group-mates)
  const int j = bid >> 5;        // WG-in-group 0..7
  const int tid = threadIdx.x;
  const int w = tid >> 6;        // wave 0..3 = K-quarter, owns col-tile w
  const int lane = tid & 63;
  const int l31 = lane & 31;
  const int hi = lane >> 5;      // k-half 0..1

  const int n0 = j * 128 + w * 32;   // wave's OWN 32-col base (tile w)
  const int m0 = g * RGRP;           // group row base

  // ---- persistent W fragments: 4 tiles x 16 kk = 256 regs (AGPR file) ----
  s8v bw[4][16];
#pragma unroll
  for (int idx = 0; idx < 4; idx++) {
    const int c = (w + idx) & 3;
    const unsigned short* wp =
        wbf + (size_t)(j * 128 + c * 32 + l31) * RS + w * 256 + hi * 8;
#pragma unroll
    for (int kk = 0; kk < 16; kk++) bw[idx][kk] = *(const s8v*)(wp + kk * 16);
  }

  // ---- input-proj Win fragments hi/lo for OWN tile cols ----
  union U8 { s8v v; unsigned short u[8]; };
  U8 whi, wlo;
  {
    const float* p = Win + (n0 + l31) * NI + hi * 8;
#pragma unroll
    for (int i = 0; i < 8; i++) {
      float f = p[i];
      unsigned short h16 = f2bf(f);
      whi.u[i] = h16;
      wlo.u[i] = f2bf(f - bf2f(h16));
    }
  }

  int* gflags = flags + g * 32;                 // this group's 32 wave-flags
  int* myflag = gflags + 4 * j + w;             // publish slot
  const int* pollp = gflags + 8 * w;            // 8 producer flags, 32B
  const float* xrow = x + (size_t)(m0 + l31) * SL * NI + hi * 8;
  // A-frag global base: c8 = 32w + 2kk + hi, row = m0 + l31
  const size_t ab_off = (((size_t)(32 * w + hi) * NB) + m0 + l31) << 4;
  char* wct = ctile + w * 2048;                 // this wave's 32x32 C tile
  int dead = 0;

  for (int t = 0; t < SL; t++) {
    const char* hsrc = (const char*)((t & 1) ? hB : hA);
    char* hdst = (char*)((t & 1) ? hA : hB);

    // ---- x(t) loads (handshake-independent; fly into the poll's drain) ----
    float4 xa = *(const float4*)(xrow + (size_t)t * NI);
    float4 xb = *(const float4*)(xrow + (size_t)t * NI + 4);

    // ---- per-wave poll: all lanes, broadcast 32B flag read, no barrier ----
    if (!dead) {
      int spins = 0;
      for (;;) {
        u4v f0, f1;
        ld_flags8(pollp, f0, f1);
        int m01 = min((int)f0.x, (int)f0.y), m23 = min((int)f0.z, (int)f0.w);
        int m45 = min((int)f1.x, (int)f1.y), m67 = min((int)f1.z, (int)f1.w);
        if (min(min(m01, m23), min(m45, m67)) >= t) break;
        __builtin_amdgcn_s_sleep(1);
        if (++spins > (1 << 12)) { dead = 1; break; }   // sticky: degrade, never hang
      }
    }

    // ---- issue all 16 direct A-frag loads (K-quarter, coalesced 16B/lane) ----
    u4v al[16];
#pragma unroll
    for (int kk = 0; kk < 16; kk++)
      al[kk] = ld_llc_b128(hsrc + ab_off + (size_t)kk * (2 * NB * 16));

    // ---- x fragments hi/lo (x regs valid: poll drained vmcnt) ----
    U8 xhi, xlo;
    {
      float xf[8] = {xa.x, xa.y, xa.z, xa.w, xb.x, xb.y, xb.z, xb.w};
#pragma unroll
      for (int i = 0; i < 8; i++) {
        unsigned short h16 = f2bf(xf[i]);
        xhi.u[i] = h16;
        xlo.u[i] = f2bf(xf[i] - bf2f(h16));
      }
    }

    // ---- input projection into OWN-tile acc (overlaps A-load flight) ----
    f16v acc[4];
    {
      f16v z = {};
      z = __builtin_amdgcn_mfma_f32_32x32x16_bf16(xhi.v, whi.v, z, 0, 0, 0);
      z = __builtin_amdgcn_mfma_f32_32x32x16_bf16(xlo.v, whi.v, z, 0, 0, 0);
      acc[0] = __builtin_amdgcn_mfma_f32_32x32x16_bf16(xhi.v, wlo.v, z, 0, 0, 0);
      f16v zz = {};
      acc[1] = zz; acc[2] = zz; acc[3] = zz;
    }

    // ---- K-quarter MFMAs, counted-vmcnt consumption (4 frags per wait) ----
#define KBLK(K0)                                                            \
    _Pragma("unroll")                                                       \
    for (int kk = K0; kk < K0 + 4; kk++) {                                  \
      union AU { u4v u; s8v s; } au; au.u = al[kk];                         \
      _Pragma("unroll")                                                     \
      for (int idx = 0; idx < 4; idx++)                                     \
        acc[idx] = __builtin_amdgcn_mfma_f32_32x32x16_bf16(au.s, bw[idx][kk], acc[idx], 0, 0, 0); \
    }
    WAIT_VM(12); KBLK(0)
    WAIT_VM(8);  KBLK(4)
    WAIT_VM(4);  KBLK(8)
    WAIT_VM(0);  KBLK(12)
#undef KBLK

    // ---- write partials for non-owned tiles to LDS (slot = tile*4 + w) ----
#pragma unroll
    for (int idx = 1; idx < 4; idx++) {
      const int c = (w + idx) & 3;
      char* slot = psm + (((c << 2) | w) << 12) + (size_t)l31 * 4;
#pragma unroll
      for (int r = 0; r < 16; r++)
        *(float*)(slot + (hi * 16 + r) * 128) = acc[idx][r];
    }
    __syncthreads();   // bar1: partials visible

    // ---- reduce own tile: acc[0] + 3 partials from LDS ----
    f16v own = acc[0];
#pragma unroll
    for (int idx = 1; idx < 4; idx++) {
      const int wp = (w + idx) & 3;    // producer wave
      const char* slot = psm + (((w << 2) | wp) << 12) + (size_t)l31 * 4;
#pragma unroll
      for (int r = 0; r < 16; r++)
        own[r] += *(const float*)(slot + (hi * 16 + r) * 128);
    }

    // ---- tanh -> bf16 -> per-wave LDS C-tile (row=(r&3)+8(r>>2)+4hi, col=l31) ----
#pragma unroll
    for (int r = 0; r < 16; r++) {
      const int row = (r & 3) + 8 * (r >> 2) + 4 * hi;
      *(unsigned short*)(wct + row * 64 + l31 * 2) = f2bf(fast_tanh(own[r]));
    }
    asm volatile("s_waitcnt lgkmcnt(0)" ::: "memory");   // wave-local transpose
    __builtin_amdgcn_sched_barrier(0);
    // ---- transpose-read C tile -> hx-layout LLC stores (coalesced) ----
    {
      const int row = lane >> 1, c = lane & 1;
      u4v v0 = *(const u4v*)(wct + row * 64 + c * 16);
      u4v v1 = *(const u4v*)(wct + row * 64 + c * 16 + 32);
      char* g0 = hdst + ((((size_t)(n0 >> 3) + c) * NB + m0 + row) << 4);
      char* g1 = hdst + ((((size_t)(n0 >> 3) + c + 2) * NB + m0 + row) << 4);
      st_llc_b128(g0, v0);
      st_llc_b128(g1, v1);
    }
    WAIT_VM(0);          // only this wave's 2 stores outstanding -> cheap
    if (lane == 0) st_llc_b32(myflag, t + 1);   // per-wave publish, fire-and-forget
    __syncthreads();     // bar2: protect partial slots (and wct) for next step
  }
}

// y = h_final @ Wout^T + b ; h in hx layout: elem (b,k) at hx[k>>3][b][k&7]
__global__ __launch_bounds__(256) void yout_kernel(
    const unsigned short* __restrict__ h, const float* __restrict__ Wout,
    const float* __restrict__ bias, float* __restrict__ y) {
  const int tid = threadIdx.x;
  const int b = (blockIdx.x << 4) + (tid >> 4);
  const int o = tid & 15;
  const float* wr = Wout + (o << 10);
  float s = 0.0f;
  for (int k8 = 0; k8 < RS / 8; k8++) {
    const unsigned short* hc = h + (((size_t)k8 * NB + b) << 3);
#pragma unroll
    for (int i = 0; i < 8; i++) s += bf2f(hc[i]) * wr[k8 * 8 + i];
  }
  y[(b << 4) + o] = s + bias[o];
}

extern "C" void kernel_launch(void* const* d_in, const int* in_sizes, int n_in,
                              void* d_out, int out_size, void* d_ws, size_t ws_size,
                              hipStream_t stream) {
  const float* x = (const float*)d_in[0];
  const float* Win = (const float*)d_in[1];
  const float* W = (const float*)d_in[2];
  const float* Wout = (const float*)d_in[3];
  const float* bias = (const float*)d_in[4];
  float* y = (float*)d_out;

  char* ws = (char*)d_ws;
  unsigned short* hA = (unsigned short*)ws;                  // 2 MB (final h)
  unsigned short* hB = (unsigned short*)(ws + (1 << 21));    // 2 MB
  unsigned short* wbf = (unsigned short*)(ws + (2 << 21));   // 2 MB (W bf16)
  int* flags = (int*)(ws + 3 * (size_t)(1 << 21));           // 16 KB wave-flags

  (void)hipFuncSetAttribute((const void*)esn_kernel,
                            hipFuncAttributeMaxDynamicSharedMemorySize, 73728);

  prep_kernel<<<4096, 256, 0, stream>>>(W, wbf, (uint4*)hA, flags);
  esn_kernel<<<NGRP * WPG, 256, 73728, stream>>>(x, Win, wbf, hA, hB, flags);
  yout_kernel<<<64, 256, 0, stream>>>(hA, Wout, bias, y);
}